// Round 8
// baseline (105.484 us; speedup 1.0000x reference)
//
#include <hip/hip_runtime.h>
#include <math.h>

#define BATCH 256
#define M 48
#define T 80
#define NF 6
#define EMIT 10
#define MM (M*M)        // 2304
#define NW 8            // waves per block
#define LOG2PI 1.8378770664093453f

typedef unsigned int u32;
typedef unsigned long long u64;

// Raw workgroup sync: drains LDS (lgkm) only -- async global_load_lds DMA
// (vmcnt) stays in flight. "memory" clobber stops compiler caching LDS in regs.
#define WGSYNC()     __asm__ __volatile__("s_waitcnt lgkmcnt(0)\ns_barrier" ::: "memory")
#define WGSYNC_ALL() __asm__ __volatile__("s_waitcnt vmcnt(0) lgkmcnt(0)\ns_barrier" ::: "memory")

// 8 waves/block. Wave-parallel phases (E-step, softmax, greedy) run
// REDUNDANTLY on all waves (free: wall == one-wave time; identical-value
// shared writes are race-safe). Deep work (DMA, keys, radix histograms,
// stat346, adjacency, selector M-step, final M-step) is SPLIT 8 ways with
// lgkm-only barriers. EM state ping-pongs and is packed float4/float2 to
// shorten the per-iteration LDS chain.
__global__ __launch_bounds__(512, 1)
void em_kernel(const float* __restrict__ g_logits,
               const float* __restrict__ g_traj,
               const float* __restrict__ g_cov,
               float* __restrict__ g_out)
{
    const int b = blockIdx.x;
    const int tid = threadIdx.x;
    const int lane = tid & 63;
    const int wv = tid >> 6;
    const int SEL[3] = {29, 49, 79};

    // ---- LDS ~141 KB ----
    __shared__ __align__(16) float s_txy[M*T*2];    // staged traj (DMA)
    __shared__ __align__(16) float s_cv4[M*T*4];    // staged cov (DMA)
    __shared__ float s_adj[MM];
    __shared__ float s_logits[M];
    __shared__ float s_probas[M];
    __shared__ float s_tsel[M*6];                   // [m][tt][d]
    __shared__ float s_d1[M*3];
    __shared__ __align__(16) float s_csel[M*3*4];   // [m][tt]{c00,c01,c11,pad}
    __shared__ __align__(16) float s_Pm[M*8];       // slots: 0-2=n0..2, 4-6=n3..5
    __shared__ __align__(16) float4 s_st[2][NF*3];  // {p00,p01,p11,ld} ping-pong
    __shared__ __align__(8)  float2 s_t6[2][NF*3];  // {tx,ty}
    __shared__ float s_probas6[2][NF];
    __shared__ int   s_idx[8];
    __shared__ __align__(16) u32 s_hist[NW][4][256]; // [wave][round] private
    __shared__ u32 s_statc[NW], s_statm[NW];

    const float* traj_b = g_traj + (size_t)b*(M*T*2);
    const float* cov_b  = g_cov  + (size_t)b*(M*T*4);

    // ========== direct gathers (redundant per wave) ==========
    float myLogit = -1e30f;
    if (lane < M) myLogit = g_logits[b*M + lane];
    float selx[3], sely[3], cc0[3], cc1[3], cc2[3];
    #pragma unroll
    for (int r = 0; r < 3; ++r) {
        int i = lane + r*64;
        if (i < M*3) {
            int m = i/3, tt = i - (i/3)*3;
            float2 xy = ((const float2*)traj_b)[m*T + SEL[tt]];
            float4 cv = ((const float4*)cov_b)[m*T + SEL[tt]];
            selx[r]=xy.x; sely[r]=xy.y; cc0[r]=cv.x; cc1[r]=cv.y; cc2[r]=cv.w;
        }
    }

    // ========== DMA staging, split 8 ways (per-wave vmcnt) ==========
    __builtin_amdgcn_sched_barrier(0);
    {
        const char* gt = (const char*)traj_b + lane*16;
        char* lt = (char*)s_txy;
        #pragma unroll 2
        for (int k = wv; k < 30; k += NW)
            __builtin_amdgcn_global_load_lds(
                (const __attribute__((address_space(1))) u32*)(gt + k*1024),
                (__attribute__((address_space(3))) u32*)(lt + k*1024), 16, 0, 0);
        const char* gc = (const char*)cov_b + lane*16;
        char* lc = (char*)s_cv4;
        #pragma unroll 2
        for (int k = wv; k < 60; k += NW)
            __builtin_amdgcn_global_load_lds(
                (const __attribute__((address_space(1))) u32*)(gc + k*1024),
                (__attribute__((address_space(3))) u32*)(lc + k*1024), 16, 0, 0);
    }
    __builtin_amdgcn_sched_barrier(0);

    // ========== zero own hist buffers (program-order before own atomics) ====
    {
        uint4* hz = (uint4*)&s_hist[wv][0][0];     // 4*256 u32 = 256 uint4
        #pragma unroll
        for (int k = 0; k < 4; ++k) hz[lane + k*64] = make_uint4(0,0,0,0);
    }

    // ========== stage selector data (redundant identical writes) ==========
    if (lane < M) s_logits[lane] = myLogit;
    #pragma unroll
    for (int r = 0; r < 3; ++r) {
        int i = lane + r*64;
        if (i < M*3) {
            int m = i/3, tt = i - (i/3)*3;
            s_tsel[m*6+tt*2+0] = selx[r];
            s_tsel[m*6+tt*2+1] = sely[r];
            s_d1[i] = selx[r]*selx[r] + sely[r]*sely[r];
            s_csel[i*4+0]=cc0[r]; s_csel[i*4+1]=cc1[r]; s_csel[i*4+2]=cc2[r]; s_csel[i*4+3]=0.f;
        }
    }

    // ========== softmax (in-wave, registers; redundant per wave) ==========
    float mx = myLogit;
    #pragma unroll
    for (int off = 32; off; off >>= 1) mx = fmaxf(mx, __shfl_xor(mx, off));
    float pe = (lane < M) ? __expf(myLogit - mx) : 0.f;
    float psum = pe;
    #pragma unroll
    for (int off = 32; off; off >>= 1) psum += __shfl_xor(psum, off);
    const float proba = pe / psum;
    if (lane < M) s_probas[lane] = proba;

    // ========== SQUARED distance keys: 4.5/thread + round-1 histogram ====
    const bool v5 = (tid < MM - 4*512);          // 256 threads own a 5th key
    u32 key[5];
    {
        u32* h0 = &s_hist[wv][0][0];
        #pragma unroll
        for (int j = 0; j < 5; ++j) {
            if (j == 4 && !v5) { key[j] = 0xFFFFFFFFu; continue; }
            int e = tid + j*512;
            int m = e/M, n = e - (e/M)*M;
            float dot = s_tsel[m*6+4]*s_tsel[n*6+4] + s_tsel[m*6+5]*s_tsel[n*6+5];
            float v = s_d1[m*3+2] + s_d1[n*3+2] - 2.0f*dot;
            key[j] = __float_as_uint(fmaxf(v, 0.0f));  // nonneg: uint order == float order
            atomicAdd(&h0[key[j] >> 24], 1u);
        }
    }

    // ========== exact order stat 345: 4-round radix over split keys ==========
    int target = 345;
    u32 prefix = 0u, pmask = 0u;
    #pragma unroll 1
    for (int r = 0; r < 4; ++r) {
        const int shift = 24 - 8*r;
        if (r) {
            u32* hr = &s_hist[wv][r][0];
            #pragma unroll
            for (int j = 0; j < 5; ++j) {
                if (j == 4 && !v5) continue;
                if ((key[j] & pmask) == prefix)
                    atomicAdd(&hr[(key[j] >> shift) & 255u], 1u);
            }
        }
        WGSYNC();   // own atomics drained; partners' partials visible
        u32 hx=0, hy=0, hz=0, hw=0;
        #pragma unroll
        for (int w = 0; w < NW; ++w) {
            uint4 h = ((const uint4*)&s_hist[w][r][0])[lane];
            hx += h.x; hy += h.y; hz += h.z; hw += h.w;
        }
        uint4 hv = make_uint4(hx, hy, hz, hw);
        u32 s4 = hv.x + hv.y + hv.z + hv.w;
        u32 cum = s4;
        #pragma unroll
        for (int off = 1; off < 64; off <<= 1) {
            u32 u = __shfl_up(cum, off);
            if (lane >= off) cum += u;
        }
        u64 bmask = __ballot(cum > (u32)target);
        int g = __builtin_ctzll(bmask);
        int dig = 0; u32 binstart = 0;
        if (lane == g) {
            u32 exc = cum - s4;
            int bi2 = lane*4;
            if (exc + hv.x > (u32)target)      { dig = bi2;   binstart = exc; }
            else { exc += hv.x;
                if (exc + hv.y > (u32)target)  { dig = bi2+1; binstart = exc; }
                else { exc += hv.y;
                    if (exc + hv.z > (u32)target) { dig = bi2+2; binstart = exc; }
                    else { exc += hv.z;            dig = bi2+3; binstart = exc; } } }
        }
        dig = __shfl(dig, g);
        binstart = (u32)__shfl((int)binstart, g);
        target -= (int)binstart;
        prefix |= ((u32)dig) << shift;
        pmask  |= (255u << shift);
    }
    const u32 k1 = prefix;                 // squared order stat 345
    const float v1f = sqrtf(__uint_as_float(k1));

    // ========== order stat 346: split partials + 1-barrier combine ==========
    {
        u32 cnt = 0, mng = 0xFFFFFFFFu;
        #pragma unroll
        for (int j = 0; j < 5; ++j) {
            if (j == 4 && !v5) continue;
            if (key[j] <= k1) cnt++;
            else mng = (key[j] < mng) ? key[j] : mng;
        }
        #pragma unroll
        for (int off = 32; off > 0; off >>= 1) {
            cnt += __shfl_down(cnt, off);
            u32 mo = (u32)__shfl_down((int)mng, off);
            mng = (mo < mng) ? mo : mng;
        }
        if (lane == 0) { s_statc[wv] = cnt; s_statm[wv] = mng; }
    }
    WGSYNC();
    float v2f;
    {
        u32 ct = 0, mt = 0xFFFFFFFFu;
        #pragma unroll
        for (int w = 0; w < NW; ++w) {
            ct += s_statc[w];
            if (s_statm[w] < mt) mt = s_statm[w];
        }
        v2f = (ct >= 347u) ? v1f : sqrtf(__uint_as_float(mt));
    }
    const float qi = 0.15f * 2303.0f;
    const float fr = qi - floorf(qi);
    const float thr = v1f*(1.0f - fr) + v2f*fr;

    // exact squared threshold: dthr = max{u : fl(sqrt(u)) <= thr}
    float dthr;
    {
        u32 ub = __float_as_uint(thr*thr);
        while (sqrtf(__uint_as_float(ub)) > thr) --ub;        // <=2 iters
        while (sqrtf(__uint_as_float(ub+1u)) <= thr) ++ub;    // <=2 iters
        dthr = __uint_as_float(ub);
    }

    // ========== adjacency, squared-space (split: 4.5/thread) ==========
    #pragma unroll
    for (int j = 0; j < 5; ++j) {
        if (j == 4 && !v5) continue;
        int e = tid + j*512;
        int m = e/M, n = e - (e/M)*M;
        float d0 = s_tsel[m*6+0]*s_tsel[n*6+0] + s_tsel[m*6+1]*s_tsel[n*6+1];
        float v0 = fmaxf(s_d1[m*3+0] + s_d1[n*3+0] - 2.0f*d0, 0.0f);
        float d1v = s_tsel[m*6+2]*s_tsel[n*6+2] + s_tsel[m*6+3]*s_tsel[n*6+3];
        float v1 = fmaxf(s_d1[m*3+1] + s_d1[n*3+1] - 2.0f*d1v, 0.0f);
        bool a = (__uint_as_float(key[j]) <= dthr) && (v0 <= dthr) && (v1 <= dthr);
        s_adj[e] = a ? 1.0f : 0.0f;
    }
    WGSYNC();

    // ========== greedy selection (redundant per wave) ==========
    const int m = (lane < M) ? lane : (M-1);
    {
        float base = 0.f;
        #pragma unroll
        for (int n = 0; n < M; ++n) base += s_adj[n*M+m] * s_probas[n];
        float worked = 1.f;
        #pragma unroll 1
        for (int k = 0; k < NF; ++k) {
            float sc = (lane < M) ? base*worked : -1.f;
            int bi = lane;
            #pragma unroll
            for (int off = 32; off; off >>= 1) {
                float so = __shfl_down(sc, off);
                int io = __shfl_down(bi, off);
                if (so > sc || (so == sc && io < bi)) { sc = so; bi = io; }
            }
            int amax = __shfl(bi, 0);   // first-max == jnp.argmax
            if (lane == 0) s_idx[k] = amax;
            worked *= (1.f - s_adj[amax*M+m]);
        }
    }

    // ========== EM init -> buffer 0 (redundant identical writes) ==========
    if (lane < NF) {
        float mx6 = -1e30f;
        #pragma unroll
        for (int j = 0; j < NF; ++j) mx6 = fmaxf(mx6, s_logits[s_idx[j]]);
        float sum6 = 0.f;
        #pragma unroll
        for (int j = 0; j < NF; ++j) sum6 += __expf(s_logits[s_idx[j]] - mx6);
        s_probas6[0][lane] = __expf(s_logits[s_idx[lane]] - mx6) / sum6;
    }
    if (lane < NF*3) {
        int n = lane/3, tt = lane - (lane/3)*3;
        int m0 = s_idx[n];
        s_t6[0][lane] = make_float2(s_tsel[m0*6+tt*2+0], s_tsel[m0*6+tt*2+1]);
        float c00 = s_csel[(m0*3+tt)*4+0];
        float c01 = s_csel[(m0*3+tt)*4+1];
        float c11 = s_csel[(m0*3+tt)*4+2];
        float det = c00*c11 - c01*c01;
        float rdet = __fdividef(1.0f, det);
        s_st[0][lane] = make_float4(c11*rdet, -c01*rdet, c00*rdet, __logf(det));
    }

    // ========== EM loop: redundant E-step + SPLIT selector M-step ==========
    float tm0=s_tsel[m*6+0], tm1=s_tsel[m*6+1], tm2=s_tsel[m*6+2],
          tm3=s_tsel[m*6+3], tm4=s_tsel[m*6+4], tm5=s_tsel[m*6+5];
    const int gid = tid >> 3;          // 8-lane group id; 18 active (waves 0-2)
    const int sub = tid & 7;
    const int gn  = gid/3, gtt = gid - (gid/3)*3;      // valid when gid<18
    const int gslot = (gn < 3) ? gn : gn + 1;

    #pragma unroll 1
    for (int it = 0; it < EMIT; ++it) {
        const int cur = it & 1, nxt = cur ^ 1;
        const float4* stC = s_st[cur];
        const float2* t6C = s_t6[cur];
        const float*  p6C = s_probas6[cur];

        // ---- E-step (all waves, lane = m): packed broadcast LDS reads ----
        float num[NF]; float den = 1e-8f;
        #pragma unroll
        for (int n = 0; n < NF; ++n) {
            float4 p0 = stC[n*3+0], p1 = stC[n*3+1], p2 = stC[n*3+2];
            float2 a0 = t6C[n*3+0], a1 = t6C[n*3+1], a2 = t6C[n*3+2];
            float lsum = p0.w + p1.w + p2.w;
            float dx0 = a0.x-tm0, dy0 = a0.y-tm1;
            float dx1 = a1.x-tm2, dy1 = a1.y-tm3;
            float dx2 = a2.x-tm4, dy2 = a2.y-tm5;
            float q = p0.x*dx0*dx0 + 2.f*p0.y*dx0*dy0 + p0.z*dy0*dy0
                    + p1.x*dx1*dx1 + 2.f*p1.y*dx1*dy1 + p1.z*dy1*dy1
                    + p2.x*dx2*dx2 + 2.f*p2.y*dx2*dy2 + p2.z*dy2*dy2;
            num[n] = (__expf(-3.f*LOG2PI - 0.5f*lsum - 0.5f*q) + 1e-8f) * p6C[n];
            den += num[n];
        }
        float f = __fdividef(proba, den);
        if (lane < M) {   // identical-value writes from all waves: race-safe
            *(float4*)&s_Pm[m*8]   = make_float4(num[0]*f, num[1]*f, num[2]*f, 0.f);
            *(float4*)&s_Pm[m*8+4] = make_float4(num[3]*f, num[4]*f, num[5]*f, 0.f);
        }
        if (it == EMIT-1) break;

        // ---- selector M-step SPLIT: 18 items x 8-lane groups, 6-deep loops ----
        if (gid < 18) {
            float SP=0,S1x=0,S1y=0,Sxx=0,Sxy=0,Syy=0,C0=0,C1=0,C2=0;
            #pragma unroll
            for (int k = 0; k < 6; ++k) {
                int mm = sub*6 + k;
                float p = s_Pm[mm*8 + gslot];     // own-wave writes: in-order visible
                float x = s_tsel[mm*6+gtt*2+0];
                float y = s_tsel[mm*6+gtt*2+1];
                float4 c4 = *(const float4*)&s_csel[(mm*3+gtt)*4];
                SP += p; S1x += p*x; S1y += p*y;
                Sxx += p*x*x; Sxy += p*x*y; Syy += p*y*y;
                C0 += p*c4.x; C1 += p*c4.y; C2 += p*c4.z;
            }
            #define R8(v) { v += __shfl_down(v,4); v += __shfl_down(v,2); v += __shfl_down(v,1); }
            R8(SP) R8(S1x) R8(S1y) R8(Sxx) R8(Sxy) R8(Syy) R8(C0) R8(C1) R8(C2)
            #undef R8
            if (sub == 0) {
                float p6 = SP;
                float tx = __fdividef(S1x, p6), ty = __fdividef(S1y, p6);
                float rp = __fdividef(1.0f, p6);
                float c00 = (C0 + (Sxx - S1x*tx)) * rp;
                float c01 = (C1 + (Sxy - S1x*ty)) * rp;
                float c11 = (C2 + (Syy - S1y*ty)) * rp;
                float det = c00*c11 - c01*c01;
                float rdet = __fdividef(1.0f, det);
                s_st[nxt][gid] = make_float4(c11*rdet, -c01*rdet, c00*rdet, __logf(det));
                s_t6[nxt][gid] = make_float2(tx, ty);
                if (gtt == 0) s_probas6[nxt][gn] = SP;
            }
        }
        WGSYNC();   // lgkm-only + s_barrier: DMA (vmcnt) stays in flight
    }

    // ========== full sync: DMA chunks + last E-step visible ==========
    WGSYNC_ALL();

    // ========== final full-T M-step: 480 lanes = (t, n) each, 48-deep ========
    float*  out_p = g_out;
    float2* out_t = (float2*)(g_out + BATCH*NF);
    float4* out_c = (float4*)(g_out + BATCH*NF + BATCH*NF*T*2);
    if (tid < T*NF) {
        int t = tid / NF, n = tid - (tid/NF)*NF;
        int slot = (n < 3) ? n : n + 1;
        float SP=0,S1x=0,S1y=0,Sxx=0,Sxy=0,Syy=0,C00=0,C01=0,C11=0;
        #pragma unroll 4
        for (int mm = 0; mm < M; ++mm) {
            float2 xy = ((const float2*)s_txy)[mm*T + t];
            float4 c4 = ((const float4*)s_cv4)[mm*T + t];
            float p  = s_Pm[mm*8 + slot];
            SP  += p;        S1x += p*xy.x;      S1y += p*xy.y;
            Sxx += p*xy.x*xy.x; Sxy += p*xy.x*xy.y; Syy += p*xy.y*xy.y;
            C00 += p*c4.x;   C01 += p*c4.y;      C11 += p*c4.w;
        }
        float p6 = SP;
        float tx = __fdividef(S1x, p6), ty = __fdividef(S1y, p6);
        float rp = __fdividef(1.0f, p6);
        float c00 = (C00 + (Sxx - S1x*tx)) * rp;
        float c01 = (C01 + (Sxy - S1x*ty)) * rp;
        float c11 = (C11 + (Syy - S1y*ty)) * rp;
        size_t o = (size_t)(b*NF + n)*T + t;
        out_t[o] = make_float2(tx, ty);
        out_c[o] = make_float4(c00, c01, c01, c11);
    }
    if (wv == 0 && lane < NF) {
        int slot = (lane < 3) ? lane : lane + 1;
        float sp = 0.f;
        for (int mm = 0; mm < M; ++mm) sp += s_Pm[mm*8 + slot];
        out_p[b*NF + lane] = sp;
    }
}

extern "C" void kernel_launch(void* const* d_in, const int* in_sizes, int n_in,
                              void* d_out, int out_size, void* d_ws, size_t ws_size,
                              hipStream_t stream) {
    const float* logits = (const float*)d_in[0];
    const float* traj   = (const float*)d_in[1];
    const float* cov    = (const float*)d_in[2];
    float* out = (float*)d_out;
    em_kernel<<<dim3(BATCH), dim3(512), 0, stream>>>(logits, traj, cov, out);
}